// Round 1
// baseline (3038.130 us; speedup 1.0000x reference)
//
#include <hip/hip_runtime.h>
#include <math.h>

#define Bsz 1024
#define Tlen 20
#define Vv 10000
#define BT (Bsz*Tlen)   // 20480

// ---------------- generic tiled fp32 GEMM: C = act(A@B + bias [+C]) ----------------
// A [M,K] row-major, B [K,N] row-major, C [M,N]. Requires M%64==0, N%64==0, K%16==0.
// ACT: 0=none, 1=exact gelu, 2=tanh
template<int ACT>
__global__ __launch_bounds__(256) void gemm_k(const float* __restrict__ A,
        const float* __restrict__ B, const float* __restrict__ bias,
        float* __restrict__ C, int M, int N, int K, int addC)
{
    __shared__ float As[16][64];   // [k][m]
    __shared__ float Bs[16][64];   // [k][n]
    const int tid = threadIdx.x;
    const int tx = tid & 15, ty = tid >> 4;
    const int row0 = blockIdx.y * 64, col0 = blockIdx.x * 64;
    const int ar = tid >> 2;          // A row in tile (0..63)
    const int ac = (tid & 3) * 4;     // A col start (0,4,8,12)
    const int br = tid >> 4;          // B row in tile (0..15)
    const int bc = (tid & 15) * 4;    // B col start
    float acc[4][4] = {};
    for (int k0 = 0; k0 < K; k0 += 16) {
        float4 av = *reinterpret_cast<const float4*>(&A[(size_t)(row0 + ar) * K + k0 + ac]);
        As[ac + 0][ar] = av.x; As[ac + 1][ar] = av.y;
        As[ac + 2][ar] = av.z; As[ac + 3][ar] = av.w;
        float4 bv = *reinterpret_cast<const float4*>(&B[(size_t)(k0 + br) * N + col0 + bc]);
        *reinterpret_cast<float4*>(&Bs[br][bc]) = bv;
        __syncthreads();
        #pragma unroll
        for (int k = 0; k < 16; ++k) {
            float4 am = *reinterpret_cast<const float4*>(&As[k][ty * 4]);
            float4 bn = *reinterpret_cast<const float4*>(&Bs[k][tx * 4]);
            float a_[4] = {am.x, am.y, am.z, am.w};
            float b_[4] = {bn.x, bn.y, bn.z, bn.w};
            #pragma unroll
            for (int i = 0; i < 4; i++)
                #pragma unroll
                for (int j = 0; j < 4; j++)
                    acc[i][j] = fmaf(a_[i], b_[j], acc[i][j]);
        }
        __syncthreads();
    }
    #pragma unroll
    for (int i = 0; i < 4; i++) {
        int r = row0 + ty * 4 + i;
        #pragma unroll
        for (int j = 0; j < 4; j++) {
            int c = col0 + tx * 4 + j;
            float v = acc[i][j];
            if (bias) v += bias[c];
            size_t idx = (size_t)r * N + c;
            if (addC) v += C[idx];
            if (ACT == 1) v = 0.5f * v * (1.f + erff(v * 0.70710678118654752f));
            else if (ACT == 2) v = tanhf(v);
            C[idx] = v;
        }
    }
}

// ---------------- LayerNorm over D=512: Y = ln(Xa (+Xb)) [*g+b] ----------------
__global__ __launch_bounds__(256) void ln_k(const float* __restrict__ Xa,
        const float* __restrict__ Xb, const float* __restrict__ g,
        const float* __restrict__ be, float* __restrict__ Y)
{
    const int row = blockIdx.x, tid = threadIdx.x;
    const size_t base = (size_t)row * 512;
    float a0 = Xa[base + tid], a1 = Xa[base + tid + 256];
    if (Xb) { a0 += Xb[base + tid]; a1 += Xb[base + tid + 256]; }
    float s = a0 + a1;
    #pragma unroll
    for (int o = 32; o; o >>= 1) s += __shfl_xor(s, o, 64);
    __shared__ float red[8];
    const int lane = tid & 63, wid = tid >> 6;
    if (!lane) red[wid] = s;
    __syncthreads();
    const float mean = (red[0] + red[1] + red[2] + red[3]) * (1.f / 512.f);
    const float d0 = a0 - mean, d1 = a1 - mean;
    float q = d0 * d0 + d1 * d1;
    #pragma unroll
    for (int o = 32; o; o >>= 1) q += __shfl_xor(q, o, 64);
    if (!lane) red[4 + wid] = q;
    __syncthreads();
    const float var = (red[4] + red[5] + red[6] + red[7]) * (1.f / 512.f);
    const float inv = rsqrtf(var + 1e-5f);
    float y0 = d0 * inv, y1 = d1 * inv;
    if (g) { y0 = y0 * g[tid] + be[tid]; y1 = y1 * g[tid + 256] + be[tid + 256]; }
    Y[base + tid] = y0; Y[base + tid + 256] = y1;
}

// ---------------- ix_t = (t==0) ? 0 : emb[actions[:, t-1]] ----------------
__global__ __launch_bounds__(256) void gather_k(const float* __restrict__ emb,
        const int* __restrict__ acts, float* __restrict__ ix, int t)
{
    const int idx = blockIdx.x * 256 + threadIdx.x;   // 1024*512
    const int b = idx >> 9, d = idx & 511;
    float v = 0.f;
    if (t > 0) { int a = acts[b * Tlen + (t - 1)]; v = emb[(size_t)a * 512 + d]; }
    ix[idx] = v;
}

// ---------------- GRU gates: h = (1-z)*n + z*ix ----------------
__global__ __launch_bounds__(256) void gru_gates_k(const float* __restrict__ gi,
        const float* __restrict__ gh, const float* __restrict__ ix,
        float* __restrict__ hx, float* __restrict__ hall_t)
{
    const int idx = blockIdx.x * 256 + threadIdx.x;   // 1024*512
    const int b = idx >> 9, d = idx & 511;
    const size_t gb = (size_t)b * 1536;
    const float ir = gi[gb + d], iz = gi[gb + 512 + d], in_ = gi[gb + 1024 + d];
    const float hr = gh[gb + d], hz = gh[gb + 512 + d], hn = gh[gb + 1024 + d];
    const float r = 1.f / (1.f + expf(-(ir + hr)));
    const float z = 1.f / (1.f + expf(-(iz + hz)));
    const float n = tanhf(in_ + r * hn);
    const float h = (1.f - z) * n + z * ix[idx];
    hx[idx] = h;
    hall_t[idx] = h;
}

// ---------------- fused logits @ W3 + log_softmax + gather + entropy ----------------
// A2 [R,64], W3 [64,V]. Per row: lse, logp[a], entropy. 32 rows/block, 256 thr.
__global__ __launch_bounds__(256) void logits_k(const float* __restrict__ A2,
        const float* __restrict__ W3, const float* __restrict__ b3,
        const float* __restrict__ wmask, const int* __restrict__ acts,
        float* __restrict__ out_lp, float* __restrict__ out_ent)
{
    __shared__ float sAT[64][32];   // [k][r]
    __shared__ float sW[64][128];
    __shared__ float sBM[128];
    const int tid = threadIdx.x;
    const int r0 = blockIdx.x * 32;
    for (int e = tid; e < 2048; e += 256) {
        int r = e >> 6, k = e & 63;
        sAT[k][r] = A2[(size_t)(r0 + r) * 64 + k];
    }
    const int lane = tid & 63, rg = tid >> 6;
    float S[8] = {0, 0, 0, 0, 0, 0, 0, 0};
    float Wm[8] = {0, 0, 0, 0, 0, 0, 0, 0};
    float LA[8];
    int aidx[8];
    #pragma unroll
    for (int i = 0; i < 8; i++) {
        LA[i] = -3.0e38f;
        int rt = r0 + rg * 8 + i;
        int t = rt >> 10, b = rt & 1023;
        aidx[i] = acts[b * Tlen + t];
    }
    __syncthreads();
    for (int c0 = 0; c0 < Vv; c0 += 128) {
        int cw = Vv - c0; if (cw > 128) cw = 128;
        for (int e = tid; e < 8192; e += 256) {
            int k = e >> 7, c = e & 127;
            sW[k][c] = (c < cw) ? W3[(size_t)k * Vv + c0 + c] : 0.f;
        }
        if (tid < 128) sBM[tid] = (tid < cw) ? (b3[c0 + tid] + wmask[c0 + tid]) : 0.f;
        __syncthreads();
        float acc0[8] = {0, 0, 0, 0, 0, 0, 0, 0};
        float acc1[8] = {0, 0, 0, 0, 0, 0, 0, 0};
        #pragma unroll 4
        for (int k = 0; k < 64; k++) {
            float w0 = sW[k][lane], w1 = sW[k][lane + 64];
            float4 aA = *reinterpret_cast<const float4*>(&sAT[k][rg * 8]);
            float4 aB = *reinterpret_cast<const float4*>(&sAT[k][rg * 8 + 4]);
            float av[8] = {aA.x, aA.y, aA.z, aA.w, aB.x, aB.y, aB.z, aB.w};
            #pragma unroll
            for (int i = 0; i < 8; i++) {
                acc0[i] = fmaf(av[i], w0, acc0[i]);
                acc1[i] = fmaf(av[i], w1, acc1[i]);
            }
        }
        const float bm0 = sBM[lane], bm1 = sBM[lane + 64];
        const bool v0 = lane < cw, v1 = (lane + 64) < cw;
        #pragma unroll
        for (int i = 0; i < 8; i++) {
            if (v0) {
                float l = acc0[i] + bm0;
                float e = expf(l);
                S[i] += e; Wm[i] += e * l;
                if (c0 + lane == aidx[i]) LA[i] = l;
            }
            if (v1) {
                float l = acc1[i] + bm1;
                float e = expf(l);
                S[i] += e; Wm[i] += e * l;
                if (c0 + 64 + lane == aidx[i]) LA[i] = l;
            }
        }
        __syncthreads();
    }
    #pragma unroll
    for (int i = 0; i < 8; i++) {
        float s = S[i], w = Wm[i], la = LA[i];
        #pragma unroll
        for (int o = 32; o; o >>= 1) {
            s += __shfl_xor(s, o, 64);
            w += __shfl_xor(w, o, 64);
            la = fmaxf(la, __shfl_xor(la, o, 64));
        }
        if (lane == 0) {
            int rt = r0 + rg * 8 + i;
            int t = rt >> 10, b = rt & 1023;
            float lse = logf(s);
            out_lp[b * Tlen + t] = la - lse;
            out_ent[b * Tlen + t] = lse - w / s;
        }
    }
}

// ---------------- critic final: val = C2 @ cr_W3 + cb3 ----------------
__global__ __launch_bounds__(256) void critic_val_k(const float* __restrict__ C2,
        const float* __restrict__ w, const float* __restrict__ bb,
        float* __restrict__ outv)
{
    const int rt = blockIdx.x * 256 + threadIdx.x;
    if (rt >= BT) return;
    const float* c = C2 + (size_t)rt * 64;
    float s = bb[0];
    #pragma unroll 16
    for (int k = 0; k < 64; k++) s = fmaf(c[k], w[k], s);
    const int t = rt >> 10, b = rt & 1023;
    outv[b * Tlen + t] = s;
}

__global__ __launch_bounds__(256) void actions_copy_k(const int* __restrict__ a,
        float* __restrict__ o)
{
    const int i = blockIdx.x * 256 + threadIdx.x;
    if (i < BT) o[i] = (float)a[i];
}

extern "C" void kernel_launch(void* const* d_in, const int* in_sizes, int n_in,
                              void* d_out, int out_size, void* d_ws, size_t ws_size,
                              hipStream_t stream)
{
    const float* img  = (const float*)d_in[0];
    const float* box  = (const float*)d_in[1];
    const int*   acts = (const int*)d_in[2];
    const float* fr_W = (const float*)d_in[3];
    const float* fr_b = (const float*)d_in[4];
    const float* b1W1 = (const float*)d_in[5];
    const float* b1b1 = (const float*)d_in[6];
    const float* b1W2 = (const float*)d_in[7];
    const float* b1b2 = (const float*)d_in[8];
    const float* b2W1 = (const float*)d_in[9];
    const float* b2b1 = (const float*)d_in[10];
    const float* b2W2 = (const float*)d_in[11];
    const float* b2b2 = (const float*)d_in[12];
    const float* lng  = (const float*)d_in[13];
    const float* lnb  = (const float*)d_in[14];
    const float* encW = (const float*)d_in[15];
    const float* encb = (const float*)d_in[16];
    const float* emb  = (const float*)d_in[17];
    const float* Wih  = (const float*)d_in[18];
    const float* bih  = (const float*)d_in[19];
    const float* Whh  = (const float*)d_in[20];
    const float* bhh  = (const float*)d_in[21];
    const float* aW1  = (const float*)d_in[22];
    const float* ab1  = (const float*)d_in[23];
    const float* aW2  = (const float*)d_in[24];
    const float* ab2  = (const float*)d_in[25];
    const float* aW3  = (const float*)d_in[26];
    const float* ab3  = (const float*)d_in[27];
    const float* cW1  = (const float*)d_in[28];
    const float* cb1  = (const float*)d_in[29];
    const float* cW2  = (const float*)d_in[30];
    const float* cb2  = (const float*)d_in[31];
    const float* cW3  = (const float*)d_in[32];
    const float* cb3  = (const float*)d_in[33];
    const float* wmask= (const float*)d_in[34];
    float* out = (float*)d_out;

    float* ws = (float*)d_ws;
    float* X    = ws;                      // 1024*512
    float* Y    = X  + 524288;
    float* T1   = Y  + 524288;
    float* T2   = T1 + 524288;
    float* HX   = T2 + 524288;
    float* IX   = HX + 524288;
    float* GI   = IX + 524288;             // 1024*1536
    float* GH   = GI + 1572864;
    float* HALL = GH + 1572864;            // 20480*512
    float* A1   = HALL + 10485760;         // 20480*64
    float* A2   = A1 + 1310720;
    // total = 19,398,656 floats = ~74 MB of ws

    const dim3 blk(256);
    const dim3 g512(8, 16);     // N=512, M=1024
    const dim3 g1536(24, 16);   // N=1536, M=1024
    const dim3 g64(1, 320);     // N=64, M=20480

    // ---- encoder ----
    // x = [img|box] @ fr_W + fr_b  (split: avoids materializing concat)
    gemm_k<0><<<g512, blk, 0, stream>>>(img, fr_W, nullptr, X, 1024, 512, 2048, 0);
    gemm_k<0><<<g512, blk, 0, stream>>>(box, fr_W + (size_t)2048 * 512, fr_b, X, 1024, 512, 256, 1);
    ln_k<<<1024, blk, 0, stream>>>(X, nullptr, nullptr, nullptr, Y);
    gemm_k<1><<<g512, blk, 0, stream>>>(Y, b1W1, b1b1, T1, 1024, 512, 512, 0);
    gemm_k<0><<<g512, blk, 0, stream>>>(T1, b1W2, b1b2, T2, 1024, 512, 512, 0);
    ln_k<<<1024, blk, 0, stream>>>(T2, X, nullptr, nullptr, Y);
    gemm_k<1><<<g512, blk, 0, stream>>>(Y, b2W1, b2b1, T1, 1024, 512, 512, 0);
    gemm_k<0><<<g512, blk, 0, stream>>>(T1, b2W2, b2b2, T2, 1024, 512, 512, 0);
    ln_k<<<1024, blk, 0, stream>>>(X, T2, lng, lnb, Y);
    gemm_k<0><<<g512, blk, 0, stream>>>(Y, encW, encb, HX, 1024, 512, 512, 0);

    // ---- GRU scan ----
    for (int t = 0; t < Tlen; ++t) {
        gather_k<<<2048, blk, 0, stream>>>(emb, acts, IX, t);
        gemm_k<0><<<g1536, blk, 0, stream>>>(IX, Whh, bhh, GH, 1024, 1536, 512, 0);
        gemm_k<0><<<g1536, blk, 0, stream>>>(HX, Wih, bih, GI, 1024, 1536, 512, 0);
        gru_gates_k<<<2048, blk, 0, stream>>>(GI, GH, IX, HX, HALL + (size_t)t * 524288);
    }

    // ---- heads (batched over B*T rows) ----
    gemm_k<2><<<g64, blk, 0, stream>>>(HALL, aW1, ab1, A1, BT, 64, 512, 0);
    gemm_k<2><<<g64, blk, 0, stream>>>(A1, aW2, ab2, A2, BT, 64, 64, 0);
    logits_k<<<640, blk, 0, stream>>>(A2, aW3, ab3, wmask, acts, out + BT, out + 2 * BT);
    gemm_k<2><<<g64, blk, 0, stream>>>(HALL, cW1, cb1, A1, BT, 64, 512, 0);
    gemm_k<2><<<g64, blk, 0, stream>>>(A1, cW2, cb2, A2, BT, 64, 64, 0);
    critic_val_k<<<80, blk, 0, stream>>>(A2, cW3, cb3, out + 3 * BT);
    actions_copy_k<<<80, blk, 0, stream>>>(acts, out);
}

// Round 2
// 1031.376 us; speedup vs baseline: 2.9457x; 2.9457x over previous
//
#include <hip/hip_runtime.h>
#include <math.h>

#define Tlen 20
#define Vv 10000
#define BT 20480

typedef __attribute__((ext_vector_type(8))) short b16x8;
typedef __attribute__((ext_vector_type(4))) float f32x4;

__device__ __forceinline__ unsigned short f2b(float f){
    union { float f; unsigned u; } v; v.f = f;
    unsigned r = v.u + 0x7FFFu + ((v.u >> 16) & 1u);
    return (unsigned short)(r >> 16);
}
__device__ __forceinline__ float b2f(unsigned short h){
    union { unsigned u; float f; } v; v.u = ((unsigned)h) << 16;
    return v.f;
}

// ---------------- fp32 tiled GEMM (encoder + critic): C = act(A@B + bias [+C]) ----------------
template<int ACT>
__global__ __launch_bounds__(256) void gemm_k(const float* __restrict__ A,
        const float* __restrict__ B, const float* __restrict__ bias,
        float* __restrict__ C, int M, int N, int K, int addC)
{
    __shared__ float As[16][64];
    __shared__ float Bs[16][64];
    const int tid = threadIdx.x;
    const int tx = tid & 15, ty = tid >> 4;
    const int row0 = blockIdx.y * 64, col0 = blockIdx.x * 64;
    const int ar = tid >> 2;
    const int ac = (tid & 3) * 4;
    const int br = tid >> 4;
    const int bc = (tid & 15) * 4;
    float acc[4][4] = {};
    for (int k0 = 0; k0 < K; k0 += 16) {
        float4 av = *reinterpret_cast<const float4*>(&A[(size_t)(row0 + ar) * K + k0 + ac]);
        As[ac + 0][ar] = av.x; As[ac + 1][ar] = av.y;
        As[ac + 2][ar] = av.z; As[ac + 3][ar] = av.w;
        float4 bv = *reinterpret_cast<const float4*>(&B[(size_t)(k0 + br) * N + col0 + bc]);
        *reinterpret_cast<float4*>(&Bs[br][bc]) = bv;
        __syncthreads();
        #pragma unroll
        for (int k = 0; k < 16; ++k) {
            float4 am = *reinterpret_cast<const float4*>(&As[k][ty * 4]);
            float4 bn = *reinterpret_cast<const float4*>(&Bs[k][tx * 4]);
            float a_[4] = {am.x, am.y, am.z, am.w};
            float b_[4] = {bn.x, bn.y, bn.z, bn.w};
            #pragma unroll
            for (int i = 0; i < 4; i++)
                #pragma unroll
                for (int j = 0; j < 4; j++)
                    acc[i][j] = fmaf(a_[i], b_[j], acc[i][j]);
        }
        __syncthreads();
    }
    #pragma unroll
    for (int i = 0; i < 4; i++) {
        int r = row0 + ty * 4 + i;
        #pragma unroll
        for (int j = 0; j < 4; j++) {
            int c = col0 + tx * 4 + j;
            float v = acc[i][j];
            if (bias) v += bias[c];
            size_t idx = (size_t)r * N + c;
            if (addC) v += C[idx];
            if (ACT == 1) v = 0.5f * v * (1.f + erff(v * 0.70710678118654752f));
            else if (ACT == 2) v = tanhf(v);
            C[idx] = v;
        }
    }
}

// ---------------- bf16 MFMA GEMM: C = act(A@Bt^T + bias) ----------------
// A [M,K] (bf16 bits, or fp32 if AF32), BT [N,K] bf16 bits (pre-transposed weights).
// Tile 64x64, 4 waves (each wave: 16 rows x 64 cols), K step 32.
// A/B frag: lane l holds elem k=(l>>4)*8+i of row/col (l&15).
// C/D: col=lane&15, row=(lane>>4)*4+reg  [verified layout, learn_hip m89/m91]
template<int ACT, int OUTF, int OUTB, int AF32>
__global__ __launch_bounds__(256) void gemm_bf_k(
        const void* __restrict__ Av, const unsigned short* __restrict__ BTp,
        const float* __restrict__ bias, float* __restrict__ Cf,
        unsigned short* __restrict__ Cb, int M, int N, int K)
{
    // stride 80B per 32-k row: quad-bank = (20*row + 4*slot) % 32 -> ~2-way only
    __shared__ __align__(16) char As[64 * 80];
    __shared__ __align__(16) char Bs[64 * 80];
    const int tid = threadIdx.x;
    const int wid = tid >> 6, lane = tid & 63;
    const int row0 = blockIdx.y * 64, col0 = blockIdx.x * 64;
    const int srow = tid >> 2, sslot = tid & 3;
    f32x4 acc[4];
    #pragma unroll
    for (int i = 0; i < 4; i++) acc[i] = (f32x4){0.f, 0.f, 0.f, 0.f};
    const int afoff = (wid * 16 + (lane & 15)) * 80 + (lane >> 4) * 16;
    for (int k0 = 0; k0 < K; k0 += 32) {
        b16x8 av, bv;
        if (AF32) {
            const float* Af = (const float*)Av + (size_t)(row0 + srow) * K + k0 + sslot * 8;
            float4 a0 = *(const float4*)Af;
            float4 a1 = *(const float4*)(Af + 4);
            av[0]=(short)f2b(a0.x); av[1]=(short)f2b(a0.y); av[2]=(short)f2b(a0.z); av[3]=(short)f2b(a0.w);
            av[4]=(short)f2b(a1.x); av[5]=(short)f2b(a1.y); av[6]=(short)f2b(a1.z); av[7]=(short)f2b(a1.w);
        } else {
            av = *(const b16x8*)((const unsigned short*)Av + (size_t)(row0 + srow) * K + k0 + sslot * 8);
        }
        bv = *(const b16x8*)(BTp + (size_t)(col0 + srow) * K + k0 + sslot * 8);
        __syncthreads();
        *(b16x8*)(As + srow * 80 + sslot * 16) = av;
        *(b16x8*)(Bs + srow * 80 + sslot * 16) = bv;
        __syncthreads();
        b16x8 af = *(const b16x8*)(As + afoff);
        #pragma unroll
        for (int ct = 0; ct < 4; ct++) {
            b16x8 bf = *(const b16x8*)(Bs + (ct * 16 + (lane & 15)) * 80 + (lane >> 4) * 16);
            acc[ct] = __builtin_amdgcn_mfma_f32_16x16x32_bf16(af, bf, acc[ct], 0, 0, 0);
        }
    }
    const int orow = row0 + wid * 16 + (lane >> 4) * 4;
    #pragma unroll
    for (int ct = 0; ct < 4; ct++) {
        int col = col0 + ct * 16 + (lane & 15);
        float bb = bias ? bias[col] : 0.f;
        #pragma unroll
        for (int r = 0; r < 4; r++) {
            float v = acc[ct][r] + bb;
            if (ACT == 2) v = tanhf(v);
            size_t idx = (size_t)(orow + r) * N + col;
            if (OUTF) Cf[idx] = v;
            if (OUTB) Cb[idx] = f2b(v);
        }
    }
}

// ---------------- transpose + convert: WT[n*K+k] = bf16(W[k*N+n]) ----------------
__global__ __launch_bounds__(256) void cvtT_k(const float* __restrict__ W,
        unsigned short* __restrict__ WT, int K, int N)
{
    int idx = blockIdx.x * 256 + threadIdx.x;
    if (idx >= N * K) return;
    int n = idx / K, k = idx - n * K;
    WT[idx] = f2b(W[(size_t)k * N + n]);
}

// ---------------- E[(t*1024+b)][d] = bf16((t==0)?0:emb[act[b][t-1]][d]) ----------------
__global__ __launch_bounds__(256) void gatherE_k(const float* __restrict__ emb,
        const int* __restrict__ acts, unsigned short* __restrict__ E)
{
    int idx = blockIdx.x * 256 + threadIdx.x;      // 20480*128
    int d4 = (idx & 127) * 4;
    int rt = idx >> 7;
    int t = rt >> 10, b = rt & 1023;
    float4 v = {0.f, 0.f, 0.f, 0.f};
    if (t) v = *(const float4*)(emb + (size_t)acts[b * Tlen + t - 1] * 512 + d4);
    ushort4 o; o.x = f2b(v.x); o.y = f2b(v.y); o.z = f2b(v.z); o.w = f2b(v.w);
    *(ushort4*)(E + (size_t)rt * 512 + d4) = o;
}

// ---------------- LayerNorm over D=512 ----------------
__global__ __launch_bounds__(256) void ln_k(const float* __restrict__ Xa,
        const float* __restrict__ Xb, const float* __restrict__ g,
        const float* __restrict__ be, float* __restrict__ Y)
{
    const int row = blockIdx.x, tid = threadIdx.x;
    const size_t base = (size_t)row * 512;
    float a0 = Xa[base + tid], a1 = Xa[base + tid + 256];
    if (Xb) { a0 += Xb[base + tid]; a1 += Xb[base + tid + 256]; }
    float s = a0 + a1;
    #pragma unroll
    for (int o = 32; o; o >>= 1) s += __shfl_xor(s, o, 64);
    __shared__ float red[8];
    const int lane = tid & 63, wid = tid >> 6;
    if (!lane) red[wid] = s;
    __syncthreads();
    const float mean = (red[0] + red[1] + red[2] + red[3]) * (1.f / 512.f);
    const float d0 = a0 - mean, d1 = a1 - mean;
    float q = d0 * d0 + d1 * d1;
    #pragma unroll
    for (int o = 32; o; o >>= 1) q += __shfl_xor(q, o, 64);
    if (!lane) red[4 + wid] = q;
    __syncthreads();
    const float var = (red[4] + red[5] + red[6] + red[7]) * (1.f / 512.f);
    const float inv = rsqrtf(var + 1e-5f);
    float y0 = d0 * inv, y1 = d1 * inv;
    if (g) { y0 = y0 * g[tid] + be[tid]; y1 = y1 * g[tid + 256] + be[tid + 256]; }
    Y[base + tid] = y0; Y[base + tid + 256] = y1;
}

// ---------------- GRU gates: reads GI fp32, GHall bf16, emb gather; writes HX fp32 + HALL fp32 ----------------
__global__ __launch_bounds__(256) void gru_gates2_k(const float* __restrict__ GI,
        const unsigned short* __restrict__ GHall, const float* __restrict__ emb,
        const int* __restrict__ acts, int t, float* __restrict__ HX,
        float* __restrict__ HALLf)
{
    const int idx = blockIdx.x * 256 + threadIdx.x;   // 1024*512
    const int b = idx >> 9, d = idx & 511;
    const size_t gb = (size_t)b * 1536;
    const size_t ghb = ((size_t)t * 1024 + b) * 1536;
    const float ir = GI[gb + d], iz = GI[gb + 512 + d], in_ = GI[gb + 1024 + d];
    const float hr = b2f(GHall[ghb + d]);
    const float hz = b2f(GHall[ghb + 512 + d]);
    const float hn = b2f(GHall[ghb + 1024 + d]);
    float ix = 0.f;
    if (t) ix = emb[(size_t)acts[b * Tlen + t - 1] * 512 + d];
    const float r = 1.f / (1.f + expf(-(ir + hr)));
    const float z = 1.f / (1.f + expf(-(iz + hz)));
    const float n = tanhf(in_ + r * hn);
    const float h = (1.f - z) * n + z * ix;
    HX[idx] = h;
    HALLf[((size_t)t << 19) + idx] = h;
}

// ---------------- fused logits MFMA + partial softmax stats ----------------
// Only unmasked cols (<5000; loop to 5056, masked cols give exp(-1000)=0 exactly).
// Outputs lse[rt] and entropy. 64 rows/block (4 waves x 16 rows), 320 blocks.
__global__ __launch_bounds__(256) void logits2_k(const unsigned short* __restrict__ A2b,
        const unsigned short* __restrict__ WT3, const float* __restrict__ b3,
        const float* __restrict__ wmask, float* __restrict__ lse_out,
        float* __restrict__ out_ent)
{
    __shared__ __align__(16) char Bs[64 * 144];   // [col][64k], 144B stride -> ~2-way banks
    __shared__ float bmS[64];
    const int tid = threadIdx.x, wid = tid >> 6, lane = tid & 63;
    const int r0 = blockIdx.x * 64;
    const size_t abase = (size_t)(r0 + wid * 16 + (lane & 15)) * 64 + (lane >> 4) * 8;
    const b16x8 af0 = *(const b16x8*)(A2b + abase);
    const b16x8 af1 = *(const b16x8*)(A2b + abase + 32);
    float S[4] = {0.f, 0.f, 0.f, 0.f}, Wm[4] = {0.f, 0.f, 0.f, 0.f};
    for (int c0 = 0; c0 < 5056; c0 += 64) {
        __syncthreads();
        #pragma unroll
        for (int i = 0; i < 2; i++) {
            int e = tid + i * 256;
            int rr = e >> 3, slot = e & 7;
            b16x8 wv = *(const b16x8*)(WT3 + (size_t)(c0 + rr) * 64 + slot * 8);
            *(b16x8*)(Bs + rr * 144 + slot * 16) = wv;
        }
        if (tid < 64) bmS[tid] = b3[c0 + tid] + wmask[c0 + tid];
        __syncthreads();
        #pragma unroll
        for (int ct = 0; ct < 4; ct++) {
            const int colb = (ct * 16 + (lane & 15)) * 144 + (lane >> 4) * 16;
            b16x8 bf0 = *(const b16x8*)(Bs + colb);
            b16x8 bf1 = *(const b16x8*)(Bs + colb + 64);
            f32x4 acc = (f32x4){0.f, 0.f, 0.f, 0.f};
            acc = __builtin_amdgcn_mfma_f32_16x16x32_bf16(af0, bf0, acc, 0, 0, 0);
            acc = __builtin_amdgcn_mfma_f32_16x16x32_bf16(af1, bf1, acc, 0, 0, 0);
            const float bm = bmS[ct * 16 + (lane & 15)];
            #pragma unroll
            for (int r = 0; r < 4; r++) {
                float l = acc[r] + bm;
                float e = expf(l);
                S[r] += e;
                Wm[r] = fmaf(e, l, Wm[r]);
            }
        }
    }
    #pragma unroll
    for (int r = 0; r < 4; r++) {
        float s = S[r], w = Wm[r];
        #pragma unroll
        for (int o = 1; o < 16; o <<= 1) {
            s += __shfl_xor(s, o, 64);
            w += __shfl_xor(w, o, 64);
        }
        if ((lane & 15) == 0) {
            int row = r0 + wid * 16 + (lane >> 4) * 4 + r;
            float l = logf(s);
            lse_out[row] = l;
            int t = row >> 10, b = row & 1023;
            out_ent[b * Tlen + t] = l - w / s;
        }
    }
}

// ---------------- logp[action]: one K=64 dot per row ----------------
__global__ __launch_bounds__(256) void la_k(const unsigned short* __restrict__ A2b,
        const unsigned short* __restrict__ WT3, const float* __restrict__ b3,
        const float* __restrict__ wmask, const int* __restrict__ acts,
        const float* __restrict__ lse, float* __restrict__ out_lp)
{
    int rt = blockIdx.x * 256 + threadIdx.x;
    if (rt >= BT) return;
    int t = rt >> 10, b = rt & 1023;
    int a = acts[b * Tlen + t];
    const unsigned short* ar = A2b + (size_t)rt * 64;
    const unsigned short* wr = WT3 + (size_t)a * 64;
    float s = 0.f;
    #pragma unroll 16
    for (int k = 0; k < 64; k++) s = fmaf(b2f(ar[k]), b2f(wr[k]), s);
    s += b3[a] + wmask[a];
    out_lp[b * Tlen + t] = s - lse[rt];
}

// ---------------- critic final ----------------
__global__ __launch_bounds__(256) void critic_val_k(const float* __restrict__ C2,
        const float* __restrict__ w, const float* __restrict__ bb,
        float* __restrict__ outv)
{
    const int rt = blockIdx.x * 256 + threadIdx.x;
    if (rt >= BT) return;
    const float* c = C2 + (size_t)rt * 64;
    float s = bb[0];
    #pragma unroll 16
    for (int k = 0; k < 64; k++) s = fmaf(c[k], w[k], s);
    const int t = rt >> 10, b = rt & 1023;
    outv[b * Tlen + t] = s;
}

__global__ __launch_bounds__(256) void actions_copy_k(const int* __restrict__ a,
        float* __restrict__ o)
{
    const int i = blockIdx.x * 256 + threadIdx.x;
    if (i < BT) o[i] = (float)a[i];
}

extern "C" void kernel_launch(void* const* d_in, const int* in_sizes, int n_in,
                              void* d_out, int out_size, void* d_ws, size_t ws_size,
                              hipStream_t stream)
{
    const float* img  = (const float*)d_in[0];
    const float* box  = (const float*)d_in[1];
    const int*   acts = (const int*)d_in[2];
    const float* fr_W = (const float*)d_in[3];
    const float* fr_b = (const float*)d_in[4];
    const float* b1W1 = (const float*)d_in[5];
    const float* b1b1 = (const float*)d_in[6];
    const float* b1W2 = (const float*)d_in[7];
    const float* b1b2 = (const float*)d_in[8];
    const float* b2W1 = (const float*)d_in[9];
    const float* b2b1 = (const float*)d_in[10];
    const float* b2W2 = (const float*)d_in[11];
    const float* b2b2 = (const float*)d_in[12];
    const float* lng  = (const float*)d_in[13];
    const float* lnb  = (const float*)d_in[14];
    const float* encW = (const float*)d_in[15];
    const float* encb = (const float*)d_in[16];
    const float* emb  = (const float*)d_in[17];
    const float* Wih  = (const float*)d_in[18];
    const float* bih  = (const float*)d_in[19];
    const float* Whh  = (const float*)d_in[20];
    const float* bhh  = (const float*)d_in[21];
    const float* aW1  = (const float*)d_in[22];
    const float* ab1  = (const float*)d_in[23];
    const float* aW2  = (const float*)d_in[24];
    const float* ab2  = (const float*)d_in[25];
    const float* aW3  = (const float*)d_in[26];
    const float* ab3  = (const float*)d_in[27];
    const float* cW1  = (const float*)d_in[28];
    const float* cb1  = (const float*)d_in[29];
    const float* cW2  = (const float*)d_in[30];
    const float* cb2  = (const float*)d_in[31];
    const float* cW3  = (const float*)d_in[32];
    const float* cb3  = (const float*)d_in[33];
    const float* wmask= (const float*)d_in[34];
    float* out = (float*)d_out;

    // ---- workspace layout (~138 MB) ----
    char* w = (char*)d_ws;
    unsigned short* WihT = (unsigned short*)w;  w += (size_t)786432 * 2;
    unsigned short* WhhT = (unsigned short*)w;  w += (size_t)786432 * 2;
    unsigned short* aW1T = (unsigned short*)w;  w += (size_t)32768 * 2;
    unsigned short* aW2T = (unsigned short*)w;  w += (size_t)4096 * 2;
    unsigned short* WT3  = (unsigned short*)w;  w += (size_t)640000 * 2;
    char* arena = w;                            w += (size_t)10485760 * 2;  // E bf16 / enc bufs / critic bufs
    unsigned short* GHall = (unsigned short*)w; w += (size_t)31457280 * 2;
    float* HX   = (float*)w;                    w += (size_t)524288 * 4;
    float* GI   = (float*)w;                    w += (size_t)1572864 * 4;
    float* HALLf = (float*)w;                   w += (size_t)10485760 * 4;
    unsigned short* A1b = (unsigned short*)w;   w += (size_t)1310720 * 2;
    unsigned short* A2b = (unsigned short*)w;   w += (size_t)1310720 * 2;
    float* lse  = (float*)w;                    w += (size_t)20480 * 4;

    unsigned short* E = (unsigned short*)arena;          // phase 1
    float* Xe  = (float*)arena;                          // phase 2 (encoder, E dead)
    float* Ye  = Xe + 524288;
    float* T1e = Ye + 524288;
    float* T2e = T1e + 524288;
    float* C1  = (float*)arena;                          // phase 4 (critic, enc dead)
    float* C2  = C1 + 1310720;

    const dim3 blk(256);

    // ---- weight transposes + E gather + batched GH GEMM ----
    cvtT_k<<<3072, blk, 0, stream>>>(Wih, WihT, 512, 1536);
    cvtT_k<<<3072, blk, 0, stream>>>(Whh, WhhT, 512, 1536);
    cvtT_k<<<128, blk, 0, stream>>>(aW1, aW1T, 512, 64);
    cvtT_k<<<16, blk, 0, stream>>>(aW2, aW2T, 64, 64);
    cvtT_k<<<2500, blk, 0, stream>>>(aW3, WT3, 64, 10000);
    gatherE_k<<<10240, blk, 0, stream>>>(emb, acts, E);
    gemm_bf_k<0, 0, 1, 0><<<dim3(24, 320), blk, 0, stream>>>(E, WhhT, bhh,
            nullptr, GHall, BT, 1536, 512);

    // ---- encoder (fp32) ----
    gemm_k<0><<<dim3(8, 16), blk, 0, stream>>>(img, fr_W, nullptr, Xe, 1024, 512, 2048, 0);
    gemm_k<0><<<dim3(8, 16), blk, 0, stream>>>(box, fr_W + (size_t)2048 * 512, fr_b, Xe, 1024, 512, 256, 1);
    ln_k<<<1024, blk, 0, stream>>>(Xe, nullptr, nullptr, nullptr, Ye);
    gemm_k<1><<<dim3(8, 16), blk, 0, stream>>>(Ye, b1W1, b1b1, T1e, 1024, 512, 512, 0);
    gemm_k<0><<<dim3(8, 16), blk, 0, stream>>>(T1e, b1W2, b1b2, T2e, 1024, 512, 512, 0);
    ln_k<<<1024, blk, 0, stream>>>(T2e, Xe, nullptr, nullptr, Ye);
    gemm_k<1><<<dim3(8, 16), blk, 0, stream>>>(Ye, b2W1, b2b1, T1e, 1024, 512, 512, 0);
    gemm_k<0><<<dim3(8, 16), blk, 0, stream>>>(T1e, b2W2, b2b2, T2e, 1024, 512, 512, 0);
    ln_k<<<1024, blk, 0, stream>>>(Xe, T2e, lng, lnb, Ye);
    gemm_k<0><<<dim3(8, 16), blk, 0, stream>>>(Ye, encW, encb, HX, 1024, 512, 512, 0);

    // ---- GRU scan: only gi = HX @ Wih stays sequential ----
    for (int t = 0; t < Tlen; ++t) {
        gemm_bf_k<0, 1, 0, 1><<<dim3(24, 16), blk, 0, stream>>>(HX, WihT, bih,
                GI, nullptr, 1024, 1536, 512);
        gru_gates2_k<<<2048, blk, 0, stream>>>(GI, GHall, emb, acts, t, HX, HALLf);
    }

    // ---- actor head (bf16 MFMA) ----
    gemm_bf_k<2, 0, 1, 1><<<dim3(1, 320), blk, 0, stream>>>(HALLf, aW1T, ab1,
            nullptr, A1b, BT, 64, 512);
    gemm_bf_k<2, 0, 1, 0><<<dim3(1, 320), blk, 0, stream>>>(A1b, aW2T, ab2,
            nullptr, A2b, BT, 64, 64);
    logits2_k<<<320, blk, 0, stream>>>(A2b, WT3, ab3, wmask, lse, out + 2 * BT);
    la_k<<<80, blk, 0, stream>>>(A2b, WT3, ab3, wmask, acts, lse, out + BT);

    // ---- critic (fp32 for accuracy on values) ----
    gemm_k<2><<<dim3(1, 320), blk, 0, stream>>>(HALLf, cW1, cb1, C1, BT, 64, 512, 0);
    gemm_k<2><<<dim3(1, 320), blk, 0, stream>>>(C1, cW2, cb2, C2, BT, 64, 64, 0);
    critic_val_k<<<80, blk, 0, stream>>>(C2, cW3, cb3, out + 3 * BT);
    actions_copy_k<<<80, blk, 0, stream>>>(acts, out);
}